// Round 1
// baseline (10548.115 us; speedup 1.0000x reference)
//
#include <hip/hip_runtime.h>

#define NN 20000      // nodes
#define NE 320000     // edges
#define XD 131        // x row: 3 coors + 128 feats
#define F  128
#define H1 514
#define MD 64

constexpr int TE = 16;   // edges per block
constexpr int TN = 8;    // nodes per block

__device__ __forceinline__ float silu(float a) {
    return a / (1.0f + __expf(-a));
}

// out[c*ostride + r] = in[r*C + c]
__global__ void transpose_pad(const float* __restrict__ in, float* __restrict__ out,
                              int R, int C, int ostride) {
    int i = blockIdx.x * 256 + threadIdx.x;
    if (i < R * C) {
        int r = i / C, c = i - r * C;
        out[c * ostride + r] = in[r * C + c];
    }
}

__global__ __launch_bounds__(256, 2) void edge_kernel(
    const float* __restrict__ x, const int* __restrict__ eidx,
    const float* __restrict__ ew1T, const float* __restrict__ eb1,
    const float* __restrict__ ew2T, const float* __restrict__ eb2,
    const float* __restrict__ cw1T, const float* __restrict__ cb1,
    const float* __restrict__ cw2, const float* __restrict__ cb2,
    float* __restrict__ m_i, float* __restrict__ mhat)
{
    __shared__ __align__(16) float ein[TE][260];   // [0..127]=feats[dst], [128..255]=feats[src]
    __shared__ __align__(16) float hbuf[TE][520];
    __shared__ __align__(16) float mij[TE][MD];
    __shared__ float rdist[TE];
    __shared__ float rcx[TE][3];
    __shared__ int   sdst[TE];

    const int tid = threadIdx.x;
    const int e0  = blockIdx.x * TE;

    // ---- stage e_in tile (coalesced: 128 consecutive floats per row-half)
    {
        const int half = tid >> 7;              // 0 -> dst feats, 1 -> src feats
        const int c    = tid & 127;
        const int base = (half ? 0 : NE) + e0;  // dst is edge_index row 1
        for (int e = 0; e < TE; ++e) {
            const int node = eidx[base + e];
            ein[e][half * 128 + c] = x[node * XD + 3 + c];
        }
    }
    if (tid < TE) {
        const int e = tid;
        const int s = eidx[e0 + e];
        const int d = eidx[NE + e0 + e];
        const float ax = x[s*XD+0] - x[d*XD+0];
        const float ay = x[s*XD+1] - x[d*XD+1];
        const float az = x[s*XD+2] - x[d*XD+2];
        rcx[e][0] = ax; rcx[e][1] = ay; rcx[e][2] = az;
        rdist[e]  = ax*ax + ay*ay + az*az;
        sdst[e]   = d;
    }
    __syncthreads();

    // ---- MLP1: h = silu(e_in @ ew1 + eb1); rel_dist column folded into init
    for (int j = tid; j < H1; j += 256) {
        const float4* wrow = reinterpret_cast<const float4*>(ew1T + j * 260);
        const float wlast = ew1T[j * 260 + 256];
        const float bj    = eb1[j];
        float acc[TE];
        #pragma unroll
        for (int e = 0; e < TE; ++e) acc[e] = fmaf(rdist[e], wlast, bj);
        for (int kk = 0; kk < 64; ++kk) {
            const float4 w = wrow[kk];
            #pragma unroll
            for (int e = 0; e < TE; ++e) {
                const float4 v = *reinterpret_cast<const float4*>(&ein[e][kk*4]);
                acc[e] = fmaf(v.x, w.x, fmaf(v.y, w.y, fmaf(v.z, w.z, fmaf(v.w, w.w, acc[e]))));
            }
        }
        #pragma unroll
        for (int e = 0; e < TE; ++e) hbuf[e][j] = silu(acc[e]);
    }
    __syncthreads();

    const int wave = tid >> 6;
    const int lane = tid & 63;

    // ---- MLP2: m_ij = silu(h @ ew2 + eb2); wave w owns edges 4w..4w+3, lane = col
    float msil[4];
    {
        const int c = lane;
        const float4* wrow = reinterpret_cast<const float4*>(ew2T + c * 516);
        float acc[4];
        #pragma unroll
        for (int i = 0; i < 4; ++i) acc[i] = eb2[c];
        for (int kk = 0; kk < 128; ++kk) {
            const float4 w = wrow[kk];
            #pragma unroll
            for (int i = 0; i < 4; ++i) {
                const int e = wave*4 + i;
                const float4 v = *reinterpret_cast<const float4*>(&hbuf[e][kk*4]);
                acc[i] = fmaf(v.x, w.x, fmaf(v.y, w.y, fmaf(v.z, w.z, fmaf(v.w, w.w, acc[i]))));
            }
        }
        const float w512 = ew2T[c*516 + 512];
        const float w513 = ew2T[c*516 + 513];
        #pragma unroll
        for (int i = 0; i < 4; ++i) {
            const int e = wave*4 + i;
            const float a = acc[i] + hbuf[e][512]*w512 + hbuf[e][513]*w513;
            msil[i] = silu(a);
            mij[e][c] = msil[i];
        }
    }
    __syncthreads();

    // ---- coor MLP: coor_w = silu(m_ij @ cw1 + cb1) @ cw2 + cb2 (all in regs)
    float pw[4] = {0.f, 0.f, 0.f, 0.f};
    #pragma unroll
    for (int cc = 0; cc < 4; ++cc) {
        const int c = lane + cc * 64;
        const float4* wrow = reinterpret_cast<const float4*>(cw1T + c * 64);
        float acc[4];
        #pragma unroll
        for (int i = 0; i < 4; ++i) acc[i] = cb1[c];
        #pragma unroll
        for (int kk = 0; kk < 16; ++kk) {
            const float4 w = wrow[kk];
            #pragma unroll
            for (int i = 0; i < 4; ++i) {
                const int e = wave*4 + i;
                const float4 v = *reinterpret_cast<const float4*>(&mij[e][kk*4]);
                acc[i] = fmaf(v.x, w.x, fmaf(v.y, w.y, fmaf(v.z, w.z, fmaf(v.w, w.w, acc[i]))));
            }
        }
        const float w2 = cw2[c];
        #pragma unroll
        for (int i = 0; i < 4; ++i) pw[i] = fmaf(silu(acc[i]), w2, pw[i]);
    }
    #pragma unroll
    for (int m = 1; m < 64; m <<= 1) {
        #pragma unroll
        for (int i = 0; i < 4; ++i) pw[i] += __shfl_xor(pw[i], m, 64);
    }
    const float cb2v = cb2[0];

    // ---- scatter: segment sums via atomics
    #pragma unroll
    for (int i = 0; i < 4; ++i) {
        const int e = wave*4 + i;
        atomicAdd(&m_i[sdst[e]*MD + lane], msil[i]);
    }
    if (lane < 12) {
        const int i = lane / 3, d = lane - i*3;
        const int e = wave*4 + i;
        atomicAdd(&mhat[sdst[e]*3 + d], (pw[i] + cb2v) * rcx[e][d]);
    }
}

__global__ __launch_bounds__(256, 2) void node_kernel(
    const float* __restrict__ x, const float* __restrict__ m_i, const float* __restrict__ mhat,
    const float* __restrict__ ng, const float* __restrict__ nb,
    const float* __restrict__ nw1T, const float* __restrict__ nb1,
    const float* __restrict__ nw2T, const float* __restrict__ nb2,
    float* __restrict__ xn)
{
    __shared__ __align__(16) float nin[TN][192];
    __shared__ __align__(16) float hid[TN][256];
    const int tid = threadIdx.x;
    const int n0  = blockIdx.x * TN;

    for (int idx = tid; idx < TN*192; idx += 256) {
        const int n = idx / 192, k = idx - n*192;
        nin[n][k] = (k < F) ? x[(n0+n)*XD + 3 + k] : m_i[(n0+n)*MD + (k - F)];
    }
    __syncthreads();

    const int wave = tid >> 6, lane = tid & 63;
    // ---- LayerNorm on feats half of nin: half-wave (32 lanes) per node
    {
        const int n  = wave*2 + (lane >> 5);
        const int l5 = lane & 31;
        float v[4]; float s = 0.f, q = 0.f;
        #pragma unroll
        for (int i = 0; i < 4; ++i) { v[i] = nin[n][l5 + 32*i]; s += v[i]; q = fmaf(v[i], v[i], q); }
        #pragma unroll
        for (int m = 1; m < 32; m <<= 1) { s += __shfl_xor(s, m, 64); q += __shfl_xor(q, m, 64); }
        const float mu  = s * (1.f/128.f);
        const float var = q * (1.f/128.f) - mu*mu;
        const float rs  = rsqrtf(var + 1e-5f);
        #pragma unroll
        for (int i = 0; i < 4; ++i) {
            const int k = l5 + 32*i;
            nin[n][k] = (v[i] - mu) * rs * ng[k] + nb[k];
        }
    }
    __syncthreads();
    // ---- hidden = silu(n_in @ nw1 + nb1), 256 cols (one per thread)
    {
        const int col = tid;
        const float4* wrow = reinterpret_cast<const float4*>(nw1T + col * 192);
        const float b = nb1[col];
        float acc[TN];
        #pragma unroll
        for (int n = 0; n < TN; ++n) acc[n] = b;
        for (int kk = 0; kk < 48; ++kk) {
            const float4 w = wrow[kk];
            #pragma unroll
            for (int n = 0; n < TN; ++n) {
                const float4 v = *reinterpret_cast<const float4*>(&nin[n][kk*4]);
                acc[n] = fmaf(v.x, w.x, fmaf(v.y, w.y, fmaf(v.z, w.z, fmaf(v.w, w.w, acc[n]))));
            }
        }
        #pragma unroll
        for (int n = 0; n < TN; ++n) hid[n][col] = silu(acc[n]);
    }
    __syncthreads();
    // ---- out = hidden @ nw2 + nb2 + feats (residual)
    {
        const int c = tid & 127;
        const int g = tid >> 7;                 // wave-uniform node group
        const float4* wrow = reinterpret_cast<const float4*>(nw2T + c * 256);
        const float b = nb2[c];
        float acc[4];
        #pragma unroll
        for (int i = 0; i < 4; ++i) acc[i] = b;
        for (int kk = 0; kk < 64; ++kk) {
            const float4 w = wrow[kk];
            #pragma unroll
            for (int i = 0; i < 4; ++i) {
                const int n = g*4 + i;
                const float4 v = *reinterpret_cast<const float4*>(&hid[n][kk*4]);
                acc[i] = fmaf(v.x, w.x, fmaf(v.y, w.y, fmaf(v.z, w.z, fmaf(v.w, w.w, acc[i]))));
            }
        }
        #pragma unroll
        for (int i = 0; i < 4; ++i) {
            const int node = n0 + g*4 + i;
            xn[node*XD + 3 + c] = acc[i] + x[node*XD + 3 + c];
        }
    }
    if (tid < TN*3) {
        const int n = tid / 3, d = tid - n*3;
        const int node = n0 + n;
        xn[node*XD + d] = x[node*XD + d] + mhat[node*3 + d];
    }
}

extern "C" void kernel_launch(void* const* d_in, const int* in_sizes, int n_in,
                              void* d_out, int out_size, void* d_ws, size_t ws_size,
                              hipStream_t stream) {
    const float* x_in = (const float*)d_in[0];
    const int*   eidx = (const int*)  d_in[1];
    const float* ew1  = (const float*)d_in[2];
    const float* eb1  = (const float*)d_in[3];
    const float* ew2  = (const float*)d_in[4];
    const float* eb2  = (const float*)d_in[5];
    const float* ng   = (const float*)d_in[6];
    const float* nb   = (const float*)d_in[7];
    const float* nw1  = (const float*)d_in[8];
    const float* nb1  = (const float*)d_in[9];
    const float* nw2  = (const float*)d_in[10];
    const float* nb2  = (const float*)d_in[11];
    const float* cw1  = (const float*)d_in[12];
    const float* cb1  = (const float*)d_in[13];
    const float* cw2  = (const float*)d_in[14];
    const float* cb2  = (const float*)d_in[15];
    float* out = (float*)d_out;

    float* ws = (float*)d_ws;
    size_t off = 0;
    auto alloc = [&](size_t n) { float* p = ws + off; off += (n + 63) & ~63ull; return p; };
    float* xA   = alloc((size_t)NN * XD);
    float* mi   = alloc((size_t)NN * MD);
    float* mh   = alloc((size_t)NN * 3);
    float* ew1T = alloc((size_t)3 * H1 * 260);
    float* ew2T = alloc((size_t)3 * MD * 516);
    float* cw1T = alloc((size_t)3 * 256 * 64);
    float* nw1T = alloc((size_t)3 * 256 * 192);
    float* nw2T = alloc((size_t)3 * 128 * 256);

    for (int l = 0; l < 3; ++l) {
        transpose_pad<<<(257*514 + 255)/256, 256, 0, stream>>>(ew1 + (size_t)l*257*514, ew1T + (size_t)l*H1*260, 257, 514, 260);
        transpose_pad<<<(514*64  + 255)/256, 256, 0, stream>>>(ew2 + (size_t)l*514*64,  ew2T + (size_t)l*MD*516, 514, 64, 516);
        transpose_pad<<<(64*256  + 255)/256, 256, 0, stream>>>(cw1 + (size_t)l*64*256,  cw1T + (size_t)l*256*64, 64, 256, 64);
        transpose_pad<<<(192*256 + 255)/256, 256, 0, stream>>>(nw1 + (size_t)l*192*256, nw1T + (size_t)l*256*192, 192, 256, 192);
        transpose_pad<<<(256*128 + 255)/256, 256, 0, stream>>>(nw2 + (size_t)l*256*128, nw2T + (size_t)l*128*256, 256, 128, 256);
    }

    for (int l = 0; l < 3; ++l) {
        const float* xc = (l == 0) ? x_in : ((l == 1) ? xA : out);
        float*       xn = (l == 0) ? xA : out;
        hipMemsetAsync(mi, 0, (size_t)NN * MD * 4, stream);
        hipMemsetAsync(mh, 0, (size_t)NN * 3 * 4, stream);
        edge_kernel<<<NE / TE, 256, 0, stream>>>(
            xc, eidx,
            ew1T + (size_t)l*H1*260, eb1 + (size_t)l*H1,
            ew2T + (size_t)l*MD*516, eb2 + (size_t)l*MD,
            cw1T + (size_t)l*256*64, cb1 + (size_t)l*256,
            cw2 + (size_t)l*256, cb2 + l,
            mi, mh);
        node_kernel<<<NN / TN, 256, 0, stream>>>(
            xc, mi, mh,
            ng + (size_t)l*F, nb + (size_t)l*F,
            nw1T + (size_t)l*256*192, nb1 + (size_t)l*256,
            nw2T + (size_t)l*128*256, nb2 + (size_t)l*F,
            xn);
    }
}

// Round 2
// 1448.535 us; speedup vs baseline: 7.2819x; 7.2819x over previous
//
#include <hip/hip_runtime.h>

typedef unsigned short u16;
typedef unsigned int   u32;
typedef __attribute__((ext_vector_type(8))) __bf16 bf16x8;
typedef __attribute__((ext_vector_type(4))) float  f32x4;

#define NN 20000      // nodes
#define NE 320000     // edges
#define XD 131        // x row: 3 coors + 128 feats
#define F  128
#define MD 64
#define H1 514
#define H1P 544       // padded hidden (silu(0)=0 padding)
#define NCH 17        // 544/32 chunks

#define GAS __attribute__((address_space(1)))
#define LAS __attribute__((address_space(3)))

constexpr int TN = 8;    // nodes per block (node kernel)

__device__ __forceinline__ float silu(float a) { return a / (1.0f + __expf(-a)); }

__device__ __forceinline__ u16 f2bf(float f) {   // fp32 -> bf16 RNE
    u32 u = __builtin_bit_cast(u32, f);
    return (u16)((u + 0x7FFFu + ((u >> 16) & 1u)) >> 16);
}

__device__ __forceinline__ f32x4 mfma16(bf16x8 a, bf16x8 b, f32x4 c) {
    return __builtin_amdgcn_mfma_f32_16x16x32_bf16(a, b, c, 0, 0, 0);
}

// ---------------- weight prep kernels (fp32 -> bf16, transpose, pad) ----------------

// w1T[l][n][k] (n<544, k<256), XOR-swizzled within each 512B row: elem k ^ ((n&7)<<3)
__global__ void prep_w1(const float* __restrict__ ew1, const float* __restrict__ eb1,
                        u16* __restrict__ w1T, float* __restrict__ w1l, float* __restrict__ eb1p) {
    int i = blockIdx.x * 256 + threadIdx.x;
    if (i >= 3 * H1P * 256) return;
    int k = i & 255;
    int n = (i >> 8) % H1P;
    int l = (i >> 8) / H1P;
    float v = (n < H1) ? ew1[(size_t)l * 257 * H1 + (size_t)k * H1 + n] : 0.f;
    w1T[(size_t)l * H1P * 256 + (size_t)n * 256 + (k ^ ((n & 7) << 3))] = f2bf(v);
    if (k == 0) {
        w1l[l * H1P + n]  = (n < H1) ? ew1[(size_t)l * 257 * H1 + (size_t)256 * H1 + n] : 0.f;
        eb1p[l * H1P + n] = (n < H1) ? eb1[l * H1 + n] : 0.f;
    }
}

// w2T[l][n][k] (n<64, k<544) plain
__global__ void prep_w2(const float* __restrict__ ew2, u16* __restrict__ w2T) {
    int i = blockIdx.x * 256 + threadIdx.x;
    if (i >= 3 * 64 * H1P) return;
    int k = i % H1P;
    int n = (i / H1P) & 63;
    int l = i / (H1P * 64);
    float v = (k < H1) ? ew2[(size_t)l * H1 * 64 + (size_t)k * 64 + n] : 0.f;
    w2T[(size_t)l * 64 * H1P + (size_t)n * H1P + k] = f2bf(v);
}

// cw1T[l][n][k] (n<256, k<64) plain
__global__ void prep_cw1(const float* __restrict__ cw1, u16* __restrict__ cw1T) {
    int i = blockIdx.x * 256 + threadIdx.x;
    if (i >= 3 * 256 * 64) return;
    int k = i & 63;
    int n = (i >> 6) & 255;
    int l = i >> 14;
    cw1T[(size_t)l * 16384 + n * 64 + k] = f2bf(cw1[(size_t)l * 16384 + k * 256 + n]);
}

// out[c*ostride + r] = in[r*C + c]   (node-MLP weights stay fp32)
__global__ void transpose_pad(const float* __restrict__ in, float* __restrict__ out,
                              int R, int C, int ostride) {
    int i = blockIdx.x * 256 + threadIdx.x;
    if (i < R * C) {
        int r = i / C, c = i - r * C;
        out[c * ostride + r] = in[r * C + c];
    }
}

// ---------------- fused edge kernel (MFMA) ----------------
// 128 edges/block, 4 waves; wave w owns edges [w*32, w*32+32)

__global__ __launch_bounds__(256, 2) void edge_mfma(
    const float* __restrict__ x, const int* __restrict__ eidx,
    const u16* __restrict__ w1T, const float* __restrict__ w1l, const float* __restrict__ eb1p,
    const u16* __restrict__ w2T, const float* __restrict__ eb2,
    const u16* __restrict__ cw1T, const float* __restrict__ cb1,
    const float* __restrict__ cw2, const float* __restrict__ cb2,
    float* __restrict__ m_i, float* __restrict__ mhat)
{
    __shared__ __align__(16) char U[34816];   // union: ein-phase | B1+Hc | mij
    __shared__ float rcx[128][4];             // rel_coors xyz + rel_dist
    __shared__ int   sdst[128];

    char* B1 = U;            // 32 x 512B  (16KB)  W1 chunk, swizzled
    char* Hc = U + 16384;    // 128 x 112B (14KB)  h chunk bf16, 56-elem rows

    const int tid = threadIdx.x;
    const int w   = tid >> 6;
    const int l   = tid & 63;
    const int lg  = l >> 4;      // k-group 0..3
    const int lc  = l & 15;      // col/row within 16-tile
    const int e0  = blockIdx.x * 128;

    if (tid < 128) {
        const int s = eidx[e0 + tid];
        const int d = eidx[NE + e0 + tid];
        float ax = x[(size_t)s*XD+0] - x[(size_t)d*XD+0];
        float ay = x[(size_t)s*XD+1] - x[(size_t)d*XD+1];
        float az = x[(size_t)s*XD+2] - x[(size_t)d*XD+2];
        rcx[tid][0] = ax; rcx[tid][1] = ay; rcx[tid][2] = az;
        rcx[tid][3] = ax*ax + ay*ay + az*az;
        sdst[tid] = d;
    }

    // ---- stage e_in in two phases (p0: feats[dst] k0..127, p1: feats[src] k128..255),
    //      load A fragments into registers (held for the whole MLP1 loop)
    bf16x8 A[2][8];   // [mt][kt]
    #pragma unroll
    for (int p = 0; p < 2; ++p) {
        __syncthreads();
        {
            const int el = tid >> 1;
            const int cb = (tid & 1) << 6;
            const int node = eidx[(p == 0 ? NE : 0) + e0 + el];
            const float* src = x + (size_t)node * XD + 3 + cb;
            u16* d16 = (u16*)U + el * 136 + cb;
            #pragma unroll
            for (int i = 0; i < 64; i += 2) {
                float a = src[i], b = src[i + 1];
                ((u32*)d16)[i >> 1] = (u32)f2bf(a) | ((u32)f2bf(b) << 16);
            }
        }
        __syncthreads();
        #pragma unroll
        for (int kt = 0; kt < 4; ++kt)
            #pragma unroll
            for (int mt = 0; mt < 2; ++mt) {
                const int row = w * 32 + mt * 16 + lc;
                A[mt][p * 4 + kt] = *(bf16x8*)(U + row * 272 + kt * 64 + lg * 16);
            }
    }
    __syncthreads();   // einS region dead; B1/Hc may be written

    // ---- m_ij accumulators (M=32 per wave, N=64), bias init
    f32x4 c2[2][4];
    #pragma unroll
    for (int nt = 0; nt < 4; ++nt) {
        const float b = eb2[nt * 16 + lc];
        #pragma unroll
        for (int mt = 0; mt < 2; ++mt) c2[mt][nt] = (f32x4){b, b, b, b};
    }

    // ---- chunk loop over H1P (17 x 32 cols): MLP1 -> silu -> MLP2-accumulate
    for (int ch = 0; ch < NCH; ++ch) {
        // stage W1 chunk (pre-swizzled in global) -> LDS, 16KB, 4KB per wave
        {
            const char* gsrc = (const char*)(w1T + (size_t)ch * 32 * 256);
            #pragma unroll
            for (int r = 0; r < 4; ++r) {
                const int off = (w * 4 + r) * 1024;
                __builtin_amdgcn_global_load_lds((const GAS u32*)(gsrc + off + l * 16),
                                                 (LAS u32*)(B1 + off), 16, 0, 0);
            }
        }
        asm volatile("s_waitcnt vmcnt(0)" ::: "memory");
        __syncthreads();

        // MLP1: two 16-col tiles
        #pragma unroll
        for (int nt = 0; nt < 2; ++nt) {
            const int col = ch * 32 + nt * 16 + lc;
            const float bias = eb1p[col];
            const float wl   = w1l[col];
            f32x4 c1[2];
            #pragma unroll
            for (int mt = 0; mt < 2; ++mt)
                #pragma unroll
                for (int r = 0; r < 4; ++r)
                    c1[mt][r] = fmaf(rcx[w * 32 + mt * 16 + lg * 4 + r][3], wl, bias);
            #pragma unroll
            for (int kt = 0; kt < 8; ++kt) {
                const int nl = nt * 16 + lc;
                const int kb = (kt * 64 + lg * 16) ^ ((nl & 7) << 4);
                bf16x8 B = *(bf16x8*)(B1 + nl * 512 + kb);
                c1[0] = mfma16(A[0][kt], B, c1[0]);
                c1[1] = mfma16(A[1][kt], B, c1[1]);
            }
            #pragma unroll
            for (int mt = 0; mt < 2; ++mt)
                #pragma unroll
                for (int r = 0; r < 4; ++r) {
                    const int row = w * 32 + mt * 16 + lg * 4 + r;
                    ((u16*)Hc)[row * 56 + nt * 16 + lc] = f2bf(silu(c1[mt][r]));
                }
        }
        // MLP2 partial accumulate (A from Hc — wave-local rows, B from global L2)
        bf16x8 A2[2];
        #pragma unroll
        for (int mt = 0; mt < 2; ++mt)
            A2[mt] = *(bf16x8*)(Hc + (w * 32 + mt * 16 + lc) * 112 + lg * 16);
        #pragma unroll
        for (int nt = 0; nt < 4; ++nt) {
            bf16x8 B = *(const bf16x8*)(w2T + (size_t)(nt * 16 + lc) * H1P + ch * 32 + lg * 8);
            c2[0][nt] = mfma16(A2[0], B, c2[0][nt]);
            c2[1][nt] = mfma16(A2[1], B, c2[1][nt]);
        }
        __syncthreads();   // all B1 reads done before next stage
    }

    // ---- silu -> m_ij: scatter-add m_i, stash bf16 m_ij in LDS (wave-local rows)
    u16* mijL = (u16*)U;   // 128 x 72 elems (144B rows)
    #pragma unroll
    for (int mt = 0; mt < 2; ++mt)
        #pragma unroll
        for (int nt = 0; nt < 4; ++nt)
            #pragma unroll
            for (int r = 0; r < 4; ++r) {
                const float v = silu(c2[mt][nt][r]);
                const int rowl = w * 32 + mt * 16 + lg * 4 + r;
                const int col  = nt * 16 + lc;
                mijL[rowl * 72 + col] = f2bf(v);
                atomicAdd(&m_i[(size_t)sdst[rowl] * MD + col], v);
            }

    // ---- coor MLP: silu(m_ij @ cw1 + cb1) @ cw2 + cb2 (B direct from L2)
    bf16x8 A3[2][2];
    #pragma unroll
    for (int mt = 0; mt < 2; ++mt)
        #pragma unroll
        for (int kt = 0; kt < 2; ++kt)
            A3[mt][kt] = *(bf16x8*)(U + (w * 32 + mt * 16 + lc) * 144 + kt * 64 + lg * 16);

    float pw[2][4] = {{0.f,0.f,0.f,0.f},{0.f,0.f,0.f,0.f}};
    #pragma unroll 4
    for (int nt = 0; nt < 16; ++nt) {
        const int col = nt * 16 + lc;
        const float b = cb1[col];
        f32x4 c3[2];
        #pragma unroll
        for (int mt = 0; mt < 2; ++mt) c3[mt] = (f32x4){b, b, b, b};
        #pragma unroll
        for (int kt = 0; kt < 2; ++kt) {
            bf16x8 B = *(const bf16x8*)(cw1T + (size_t)col * 64 + kt * 32 + lg * 8);
            c3[0] = mfma16(A3[0][kt], B, c3[0]);
            c3[1] = mfma16(A3[1][kt], B, c3[1]);
        }
        const float w2v = cw2[col];
        #pragma unroll
        for (int mt = 0; mt < 2; ++mt)
            #pragma unroll
            for (int r = 0; r < 4; ++r)
                pw[mt][r] = fmaf(silu(c3[mt][r]), w2v, pw[mt][r]);
    }
    #pragma unroll
    for (int m = 1; m < 16; m <<= 1)
        #pragma unroll
        for (int mt = 0; mt < 2; ++mt)
            #pragma unroll
            for (int r = 0; r < 4; ++r)
                pw[mt][r] += __shfl_xor(pw[mt][r], m, 16);

    const float cb2v = cb2[0];
    if (lc < 3) {
        #pragma unroll
        for (int mt = 0; mt < 2; ++mt)
            #pragma unroll
            for (int r = 0; r < 4; ++r) {
                const int rowl = w * 32 + mt * 16 + lg * 4 + r;
                const float cw = pw[mt][r] + cb2v;
                atomicAdd(&mhat[(size_t)sdst[rowl] * 3 + lc], cw * rcx[rowl][lc]);
            }
    }
}

// ---------------- node kernel (fp32, unchanged from round 1) ----------------

__global__ __launch_bounds__(256, 2) void node_kernel(
    const float* __restrict__ x, const float* __restrict__ m_i, const float* __restrict__ mhat,
    const float* __restrict__ ng, const float* __restrict__ nb,
    const float* __restrict__ nw1T, const float* __restrict__ nb1,
    const float* __restrict__ nw2T, const float* __restrict__ nb2,
    float* __restrict__ xn)
{
    __shared__ __align__(16) float nin[TN][192];
    __shared__ __align__(16) float hid[TN][256];
    const int tid = threadIdx.x;
    const int n0  = blockIdx.x * TN;

    for (int idx = tid; idx < TN*192; idx += 256) {
        const int n = idx / 192, k = idx - n*192;
        nin[n][k] = (k < F) ? x[(size_t)(n0+n)*XD + 3 + k] : m_i[(size_t)(n0+n)*MD + (k - F)];
    }
    __syncthreads();

    const int wave = tid >> 6, lane = tid & 63;
    {
        const int n  = wave*2 + (lane >> 5);
        const int l5 = lane & 31;
        float v[4]; float s = 0.f, q = 0.f;
        #pragma unroll
        for (int i = 0; i < 4; ++i) { v[i] = nin[n][l5 + 32*i]; s += v[i]; q = fmaf(v[i], v[i], q); }
        #pragma unroll
        for (int m = 1; m < 32; m <<= 1) { s += __shfl_xor(s, m, 64); q += __shfl_xor(q, m, 64); }
        const float mu  = s * (1.f/128.f);
        const float var = q * (1.f/128.f) - mu*mu;
        const float rs  = rsqrtf(var + 1e-5f);
        #pragma unroll
        for (int i = 0; i < 4; ++i) {
            const int k = l5 + 32*i;
            nin[n][k] = (v[i] - mu) * rs * ng[k] + nb[k];
        }
    }
    __syncthreads();
    {
        const int col = tid;
        const float4* wrow = reinterpret_cast<const float4*>(nw1T + (size_t)col * 192);
        const float b = nb1[col];
        float acc[TN];
        #pragma unroll
        for (int n = 0; n < TN; ++n) acc[n] = b;
        for (int kk = 0; kk < 48; ++kk) {
            const float4 w = wrow[kk];
            #pragma unroll
            for (int n = 0; n < TN; ++n) {
                const float4 v = *reinterpret_cast<const float4*>(&nin[n][kk*4]);
                acc[n] = fmaf(v.x, w.x, fmaf(v.y, w.y, fmaf(v.z, w.z, fmaf(v.w, w.w, acc[n]))));
            }
        }
        #pragma unroll
        for (int n = 0; n < TN; ++n) hid[n][col] = silu(acc[n]);
    }
    __syncthreads();
    {
        const int c = tid & 127;
        const int g = tid >> 7;
        const float4* wrow = reinterpret_cast<const float4*>(nw2T + (size_t)c * 256);
        const float b = nb2[c];
        float acc[4];
        #pragma unroll
        for (int i = 0; i < 4; ++i) acc[i] = b;
        for (int kk = 0; kk < 64; ++kk) {
            const float4 w = wrow[kk];
            #pragma unroll
            for (int i = 0; i < 4; ++i) {
                const int n = g*4 + i;
                const float4 v = *reinterpret_cast<const float4*>(&hid[n][kk*4]);
                acc[i] = fmaf(v.x, w.x, fmaf(v.y, w.y, fmaf(v.z, w.z, fmaf(v.w, w.w, acc[i]))));
            }
        }
        #pragma unroll
        for (int i = 0; i < 4; ++i) {
            const int node = n0 + g*4 + i;
            xn[(size_t)node*XD + 3 + c] = acc[i] + x[(size_t)node*XD + 3 + c];
        }
    }
    if (tid < TN*3) {
        const int n = tid / 3, d = tid - n*3;
        const int node = n0 + n;
        xn[(size_t)node*XD + d] = x[(size_t)node*XD + d] + mhat[node*3 + d];
    }
}

// ---------------- launch ----------------

extern "C" void kernel_launch(void* const* d_in, const int* in_sizes, int n_in,
                              void* d_out, int out_size, void* d_ws, size_t ws_size,
                              hipStream_t stream) {
    const float* x_in = (const float*)d_in[0];
    const int*   eidx = (const int*)  d_in[1];
    const float* ew1  = (const float*)d_in[2];
    const float* eb1  = (const float*)d_in[3];
    const float* ew2  = (const float*)d_in[4];
    const float* eb2  = (const float*)d_in[5];
    const float* ng   = (const float*)d_in[6];
    const float* nb   = (const float*)d_in[7];
    const float* nw1  = (const float*)d_in[8];
    const float* nb1  = (const float*)d_in[9];
    const float* nw2  = (const float*)d_in[10];
    const float* nb2  = (const float*)d_in[11];
    const float* cw1  = (const float*)d_in[12];
    const float* cb1  = (const float*)d_in[13];
    const float* cw2  = (const float*)d_in[14];
    const float* cb2  = (const float*)d_in[15];
    float* out = (float*)d_out;

    float* ws = (float*)d_ws;
    size_t off = 0;
    auto alloc = [&](size_t n) { float* p = ws + off; off += (n + 63) & ~63ull; return p; };
    float* xA    = alloc((size_t)NN * XD);
    float* mi    = alloc((size_t)NN * MD);
    float* mh    = alloc((size_t)NN * 3);
    float* nw1T  = alloc((size_t)3 * 256 * 192);
    float* nw2T  = alloc((size_t)3 * 128 * 256);
    float* w1l   = alloc((size_t)3 * H1P);
    float* eb1p  = alloc((size_t)3 * H1P);
    u16* w1T  = (u16*)alloc((size_t)3 * H1P * 256 / 2);
    u16* w2T  = (u16*)alloc((size_t)3 * 64 * H1P / 2);
    u16* cw1T = (u16*)alloc((size_t)3 * 256 * 64 / 2);

    prep_w1 <<<(3*H1P*256 + 255)/256, 256, 0, stream>>>(ew1, eb1, w1T, w1l, eb1p);
    prep_w2 <<<(3*64*H1P + 255)/256, 256, 0, stream>>>(ew2, w2T);
    prep_cw1<<<(3*256*64 + 255)/256, 256, 0, stream>>>(cw1, cw1T);
    for (int l = 0; l < 3; ++l) {
        transpose_pad<<<(192*256 + 255)/256, 256, 0, stream>>>(nw1 + (size_t)l*192*256, nw1T + (size_t)l*256*192, 192, 256, 192);
        transpose_pad<<<(256*128 + 255)/256, 256, 0, stream>>>(nw2 + (size_t)l*256*128, nw2T + (size_t)l*128*256, 256, 128, 256);
    }

    for (int l = 0; l < 3; ++l) {
        const float* xc = (l == 0) ? x_in : ((l == 1) ? xA : out);
        float*       xn = (l == 0) ? xA : out;
        hipMemsetAsync(mi, 0, (size_t)NN * MD * 4, stream);
        hipMemsetAsync(mh, 0, (size_t)NN * 3 * 4, stream);
        edge_mfma<<<NE / 128, 256, 0, stream>>>(
            xc, eidx,
            w1T + (size_t)l*H1P*256, w1l + (size_t)l*H1P, eb1p + (size_t)l*H1P,
            w2T + (size_t)l*64*H1P, eb2 + (size_t)l*MD,
            cw1T + (size_t)l*256*64, cb1 + (size_t)l*256,
            cw2 + (size_t)l*256, cb2 + l,
            mi, mh);
        node_kernel<<<NN / TN, 256, 0, stream>>>(
            xc, mi, mh,
            ng + (size_t)l*F, nb + (size_t)l*F,
            nw1T + (size_t)l*256*192, nb1 + (size_t)l*256,
            nw2T + (size_t)l*128*256, nb2 + (size_t)l*F,
            xn);
    }
}